// Round 2
// baseline (1129.079 us; speedup 1.0000x reference)
//
#include <hip/hip_runtime.h>
#include <stdint.h>

#define HID 128
#define CAP 128   // per-node LDS softmax-weight cache (deg ~ Binom(600k,1/50k), mean 12)

typedef __attribute__((ext_vector_type(8))) short bf16x8;
typedef __attribute__((ext_vector_type(4))) float f32x4;

__device__ __forceinline__ float bf2f(unsigned short u){
  union { unsigned int i; float f; } x; x.i = ((unsigned int)u) << 16; return x.f;
}
__device__ __forceinline__ unsigned short f2bf(float f){
  union { float f; unsigned int i; } x; x.f = f;
  unsigned int b = x.i;
  return (unsigned short)((b + 0x7fffu + ((b >> 16) & 1u)) >> 16);
}

// ---------------- dtype detection: is d_in storage fp32 (flag=1) or bf16 (flag=0)? ----
// fp32 storage read as ushort pairs: even positions are mantissa halves -> as bf16,
// exponent field is ~uniform (45% >= 140) OR exactly 0 (if values were bf16-rounded).
// genuine bf16 N(0,1) data: exponent <= ~132 and never exactly 0x0000.
__global__ void detect_dtype(const unsigned short* __restrict__ x, int* __restrict__ flag){
  if (threadIdx.x == 0 && blockIdx.x == 0){
    int czero = 0, cbig = 0;
    for (int i = 0; i < 256; ++i){
      unsigned short u = x[i];
      int ex = (u >> 7) & 0xFF;
      if ((i & 1) == 0 && u == 0) czero++;
      if (ex >= 140) cbig++;
    }
    flag[0] = (czero >= 32 || cbig >= 8) ? 1 : 0;
  }
}

// ---------------- canonicalization ----------------
struct CvList {
  const void* src[16];
  float* dst[16];
  int cnt[16];
  int n;
};
__global__ __launch_bounds__(256) void conv_weights(CvList L, const int* __restrict__ flag){
  bool isf32 = flag[0] != 0;
  for (int a = 0; a < L.n; ++a){
    const void* s = L.src[a];
    float* d = L.dst[a];
    int c = L.cnt[a];
    for (int i = blockIdx.x*256 + threadIdx.x; i < c; i += gridDim.x*256){
      d[i] = isf32 ? ((const float*)s)[i] : bf2f(((const unsigned short*)s)[i]);
    }
  }
}
__global__ __launch_bounds__(256) void conv_bf16(const void* __restrict__ src,
                                                 unsigned short* __restrict__ dst,
                                                 int n4, const int* __restrict__ flag){
  int i = blockIdx.x*256 + threadIdx.x;
  if (i >= n4) return;
  if (flag[0]){
    float4 v = ((const float4*)src)[i];
    ushort4 o; o.x = f2bf(v.x); o.y = f2bf(v.y); o.z = f2bf(v.z); o.w = f2bf(v.w);
    ((ushort4*)dst)[i] = o;
  } else {
    ((ushort4*)dst)[i] = ((const ushort4*)src)[i];
  }
}

// ---------------- precompute M = W_bond @ (W_edge @ att_edge), cbias = b_bond @ ve ----
__global__ __launch_bounds__(256) void precompute_M(
    const float* __restrict__ We, const float* __restrict__ ae,
    const float* __restrict__ Wb, const float* __restrict__ bb,
    float* __restrict__ Mout, float* __restrict__ cb)
{
  __shared__ float ve[128*12];
  int tid = threadIdx.x;
  for (int i = tid; i < 128*12; i += 256){
    int c = i / 12, lh = i % 12; int l = lh >> 2, h = lh & 3;
    float s = 0.f;
    for (int d = 0; d < 32; ++d)
      s += We[l*16384 + c*128 + h*32 + d] * ae[l*128 + h*32 + d];
    ve[i] = s;
  }
  __syncthreads();
  for (int i = tid; i < 16*12; i += 256){
    int k = i / 12, lh = i % 12;
    float s = 0.f;
    for (int c = 0; c < 128; ++c) s += Wb[k*128 + c] * ve[c*12 + lh];
    Mout[i] = s;
  }
  for (int i = tid; i < 12; i += 256){
    float s = 0.f;
    for (int c = 0; c < 128; ++c) s += bb[c] * ve[c*12 + i];
    cb[i] = s;
  }
}

// ---------------- CSR build ----------------
__global__ __launch_bounds__(256) void deg_count(const int* __restrict__ ei, int E, int* __restrict__ deg){
  int e = blockIdx.x*256 + threadIdx.x;
  if (e < E) atomicAdd(&deg[ei[E + e]], 1);
}
__global__ __launch_bounds__(256) void scan_part(const int* __restrict__ deg, int* __restrict__ part, int N){
  int base = blockIdx.x*1024;
  int s = 0;
  for (int i = threadIdx.x; i < 1024; i += 256){ int j = base + i; if (j < N) s += deg[j]; }
  __shared__ int sh[256];
  sh[threadIdx.x] = s; __syncthreads();
  for (int m = 128; m > 0; m >>= 1){ if (threadIdx.x < m) sh[threadIdx.x] += sh[threadIdx.x + m]; __syncthreads(); }
  if (threadIdx.x == 0) part[blockIdx.x] = sh[0];
}
__global__ void scan_top(int* part, int P){
  if (threadIdx.x == 0 && blockIdx.x == 0){
    int acc = 0;
    for (int i = 0; i < P; ++i){ int v = part[i]; part[i] = acc; acc += v; }
  }
}
__global__ __launch_bounds__(256) void scan_write(const int* __restrict__ deg, const int* __restrict__ part,
                                                  int* __restrict__ row, int N, int E){
  int base = blockIdx.x*1024 + threadIdx.x*4;
  int v0=0,v1=0,v2=0,v3=0;
  if (base+0 < N) v0 = deg[base+0];
  if (base+1 < N) v1 = deg[base+1];
  if (base+2 < N) v2 = deg[base+2];
  if (base+3 < N) v3 = deg[base+3];
  int s = v0+v1+v2+v3;
  __shared__ int sh[256];
  sh[threadIdx.x] = s; __syncthreads();
  for (int m = 1; m < 256; m <<= 1){
    int t = (threadIdx.x >= m) ? sh[threadIdx.x - m] : 0;
    __syncthreads();
    sh[threadIdx.x] += t;
    __syncthreads();
  }
  int excl = sh[threadIdx.x] - s + part[blockIdx.x];
  if (base+0 < N) row[base+0] = excl; excl += v0;
  if (base+1 < N) row[base+1] = excl; excl += v1;
  if (base+2 < N) row[base+2] = excl; excl += v2;
  if (base+3 < N) row[base+3] = excl;
  if (blockIdx.x == 0 && threadIdx.x == 0) row[N] = E;
}
__global__ __launch_bounds__(256) void csr_fill(const int* __restrict__ ei, int E, const int* __restrict__ row,
                                                int* __restrict__ cursor, int* __restrict__ csr_src, int* __restrict__ csr_eid){
  int e = blockIdx.x*256 + threadIdx.x;
  if (e >= E) return;
  int s = ei[e], d = ei[E + e];
  int pos = atomicAdd(&cursor[d], 1);
  int idx = row[d] + pos;
  csr_src[idx] = s;
  csr_eid[idx] = e;
}

// ---------------- MFMA GEMM: out[N,128] = A[N,K] @ W[K,128] (+bias) ----------------
// OUTMODE: 0 = fp32 internal buffer, 1 = external output, dtype per flag (1=fp32,0=bf16)
template<int K, bool INF32, int OUTMODE>
__global__ __launch_bounds__(256) void mfma_lin(const void* __restrict__ Ain,
                                                const float* __restrict__ W,
                                                const float* __restrict__ bias,
                                                void* __restrict__ Out, int N,
                                                const int* __restrict__ flag)
{
  constexpr int KP = K + 8;   // pad: break the bank alias of stride K
  __shared__ unsigned short WT[128*KP];
  int tid = threadIdx.x;
  for (int i = tid; i < K*128; i += 256){
    int k = i >> 7, ch = i & 127;
    WT[ch*KP + k] = f2bf(W[i]);
  }
  __syncthreads();
  int wid = tid >> 6, lane = tid & 63;
  int quad = lane >> 4, m = lane & 15;
  int nodeBase = blockIdx.x*64 + wid*16;
  int node = nodeBase + m;
  int nodeC = (node < N) ? node : 0;
  bf16x8 afr[K/32];
  if (INF32){
    const float* A = (const float*)Ain;
    #pragma unroll
    for (int kb = 0; kb < K/32; ++kb){
      const float4* pp = (const float4*)(A + (size_t)nodeC*K + kb*32 + quad*8);
      float4 u = pp[0], v = pp[1];
      bf16x8 f;
      f[0]=(short)f2bf(u.x); f[1]=(short)f2bf(u.y); f[2]=(short)f2bf(u.z); f[3]=(short)f2bf(u.w);
      f[4]=(short)f2bf(v.x); f[5]=(short)f2bf(v.y); f[6]=(short)f2bf(v.z); f[7]=(short)f2bf(v.w);
      afr[kb] = f;
    }
  } else {
    const unsigned short* A = (const unsigned short*)Ain;
    #pragma unroll
    for (int kb = 0; kb < K/32; ++kb)
      afr[kb] = *(const bf16x8*)(A + (size_t)nodeC*K + kb*32 + quad*8);
  }
  f32x4 acc[8] = {};
  #pragma unroll
  for (int t = 0; t < 8; ++t){
    #pragma unroll
    for (int kb = 0; kb < K/32; ++kb){
      bf16x8 bfr = *(const bf16x8*)&WT[(t*16 + m)*KP + kb*32 + quad*8];
      acc[t] = __builtin_amdgcn_mfma_f32_16x16x32_bf16(afr[kb], bfr, acc[t], 0, 0, 0);
    }
  }
  bool f32out = (OUTMODE == 0) || (flag[0] != 0);
  #pragma unroll
  for (int t = 0; t < 8; ++t){
    int ch = t*16 + m;                    // C col = lane&15
    float bv = bias ? bias[ch] : 0.f;
    #pragma unroll
    for (int r2 = 0; r2 < 4; ++r2){
      int nd = nodeBase + quad*4 + r2;    // C row = quad*4 + reg
      if (nd < N){
        float v = acc[t][r2] + bv;
        if (f32out) ((float*)Out)[(size_t)nd*HID + ch] = v;
        else        ((unsigned short*)Out)[(size_t)nd*HID + ch] = f2bf(v);
      }
    }
  }
}

// ---------------- per-head attention scores a_src/a_dst [N,4] ----------------
__global__ __launch_bounds__(128) void att_scores(const float* __restrict__ xh,
                                                  const float* __restrict__ asv,
                                                  const float* __restrict__ adv,
                                                  float* __restrict__ a_src, float* __restrict__ a_dst, int N)
{
  int c = threadIdx.x;
  float sa = asv[c], da = adv[c];
  for (int n = blockIdx.x; n < N; n += gridDim.x){
    float v = xh[(size_t)n*128 + c];
    float vs = v * sa, vd = v * da;
    #pragma unroll
    for (int m = 1; m < 32; m <<= 1){ vs += __shfl_xor(vs, m); vd += __shfl_xor(vd, m); }
    if ((c & 31) == 0){
      a_src[(size_t)n*4 + (c >> 5)] = vs;
      a_dst[(size_t)n*4 + (c >> 5)] = vd;
    }
  }
}

// ---------------- edge alpha helper: alpha_edge[e] = edge_attr[e] @ M_l + c_l ----------------
__device__ __forceinline__ void edge_ae4(const unsigned short* __restrict__ eattr, int eid,
                                         const float (*sM)[4], const float* sC, float* ae)
{
  const uint4* pp = (const uint4*)(eattr + (size_t)eid*16);
  uint4 u0 = pp[0], u1 = pp[1];
  unsigned int w[8] = {u0.x,u0.y,u0.z,u0.w,u1.x,u1.y,u1.z,u1.w};
  ae[0]=sC[0]; ae[1]=sC[1]; ae[2]=sC[2]; ae[3]=sC[3];
  #pragma unroll
  for (int k = 0; k < 16; ++k){
    unsigned short us = (unsigned short)((k & 1) ? (w[k>>1] >> 16) : (w[k>>1] & 0xffffu));
    float v = bf2f(us);
    ae[0] += v*sM[k][0]; ae[1] += v*sM[k][1]; ae[2] += v*sM[k][2]; ae[3] += v*sM[k][3];
  }
}
__device__ __forceinline__ float lrelu(float x){ return x > 0.f ? x : 0.2f*x; }
__device__ __forceinline__ float expg(float x){ return __expf(fminf(x, 0.f)); }

// ---------------- GAT aggregation: one wave per destination node ----------------
__global__ __launch_bounds__(256) void gat_agg(
    const float* __restrict__ xh, const float* __restrict__ a_src, const float* __restrict__ a_dst,
    const int* __restrict__ row, const int* __restrict__ csr_src, const int* __restrict__ csr_eid,
    const unsigned short* __restrict__ eattr, const float* __restrict__ Mmat, const float* __restrict__ cbias,
    const float* __restrict__ bconv, float* __restrict__ hout, int N, int layer)
{
  __shared__ float sM[16][4];
  __shared__ float sC[4];
  __shared__ float sW[4][CAP][4];
  int tid = threadIdx.x;
  if (tid < 64) sM[tid>>2][tid&3] = Mmat[(tid>>2)*12 + layer*4 + (tid&3)];
  if (tid < 4)  sC[tid] = cbias[layer*4 + tid];
  __syncthreads();
  int wid = tid >> 6, lane = tid & 63;
  int n = blockIdx.x*4 + wid;
  int nn = (n < N) ? n : 0;
  int r = row[nn];
  int deg = row[nn+1] - r;
  if (n >= N) deg = 0;
  float4 ad = *(const float4*)(a_dst + (size_t)nn*4);

  // pass A: alpha per incoming edge (store raw alpha in LDS), track max + sum(alpha_edge)
  float mx0=-1e30f, mx1=-1e30f, mx2=-1e30f, mx3=-1e30f;
  float s0=0.f, s1=0.f, s2=0.f, s3=0.f;
  for (int e = lane; e < deg; e += 64){
    int ce = r + e;
    int src = csr_src[ce];
    int eid = csr_eid[ce];
    float ae[4];
    edge_ae4(eattr, eid, sM, sC, ae);
    s0 += ae[0]; s1 += ae[1]; s2 += ae[2]; s3 += ae[3];
    float4 as4 = *(const float4*)(a_src + (size_t)src*4);
    float a0 = lrelu(as4.x + ad.x + ae[0]);
    float a1 = lrelu(as4.y + ad.y + ae[1]);
    float a2 = lrelu(as4.z + ad.z + ae[2]);
    float a3 = lrelu(as4.w + ad.w + ae[3]);
    if (e < CAP){ sW[wid][e][0]=a0; sW[wid][e][1]=a1; sW[wid][e][2]=a2; sW[wid][e][3]=a3; }
    mx0 = fmaxf(mx0,a0); mx1 = fmaxf(mx1,a1); mx2 = fmaxf(mx2,a2); mx3 = fmaxf(mx3,a3);
  }
  #pragma unroll
  for (int m = 1; m < 64; m <<= 1){
    mx0 = fmaxf(mx0, __shfl_xor(mx0,m)); mx1 = fmaxf(mx1, __shfl_xor(mx1,m));
    mx2 = fmaxf(mx2, __shfl_xor(mx2,m)); mx3 = fmaxf(mx3, __shfl_xor(mx3,m));
    s0 += __shfl_xor(s0,m); s1 += __shfl_xor(s1,m); s2 += __shfl_xor(s2,m); s3 += __shfl_xor(s3,m);
  }
  // self loop: alpha_edge(mean ea) == mean of incoming alpha_edge (affine, bias included
  // in each term exactly once: (sum(dot)+deg*c)/deg = dot(mean)+c).
  // deg==0: mean ea = 0 vector -> alpha_edge = c exactly.
  float invdeg = (deg > 0) ? 1.0f/(float)deg : 0.0f;
  float e0 = (deg > 0) ? s0*invdeg : sC[0];
  float e1 = (deg > 0) ? s1*invdeg : sC[1];
  float e2 = (deg > 0) ? s2*invdeg : sC[2];
  float e3 = (deg > 0) ? s3*invdeg : sC[3];
  float4 asn = *(const float4*)(a_src + (size_t)nn*4);
  float f0 = lrelu(asn.x + ad.x + e0);
  float f1 = lrelu(asn.y + ad.y + e1);
  float f2 = lrelu(asn.z + ad.z + e2);
  float f3 = lrelu(asn.w + ad.w + e3);
  mx0 = fmaxf(mx0,f0); mx1 = fmaxf(mx1,f1); mx2 = fmaxf(mx2,f2); mx3 = fmaxf(mx3,f3);

  // pass B: exp + denominator; overwrite LDS with unnormalized p
  float d0=0.f, d1=0.f, d2=0.f, d3=0.f;
  for (int e = lane; e < deg; e += 64){
    float a0,a1,a2,a3;
    if (e < CAP){ a0=sW[wid][e][0]; a1=sW[wid][e][1]; a2=sW[wid][e][2]; a3=sW[wid][e][3]; }
    else {
      int ce = r + e;
      int src = csr_src[ce]; int eid = csr_eid[ce];
      float ae[4]; edge_ae4(eattr, eid, sM, sC, ae);
      float4 as4 = *(const float4*)(a_src + (size_t)src*4);
      a0 = lrelu(as4.x + ad.x + ae[0]); a1 = lrelu(as4.y + ad.y + ae[1]);
      a2 = lrelu(as4.z + ad.z + ae[2]); a3 = lrelu(as4.w + ad.w + ae[3]);
    }
    float p0 = expg(a0-mx0), p1 = expg(a1-mx1), p2 = expg(a2-mx2), p3 = expg(a3-mx3);
    d0 += p0; d1 += p1; d2 += p2; d3 += p3;
    if (e < CAP){ sW[wid][e][0]=p0; sW[wid][e][1]=p1; sW[wid][e][2]=p2; sW[wid][e][3]=p3; }
  }
  #pragma unroll
  for (int m = 1; m < 64; m <<= 1){
    d0 += __shfl_xor(d0,m); d1 += __shfl_xor(d1,m); d2 += __shfl_xor(d2,m); d3 += __shfl_xor(d3,m);
  }
  float ps0 = expg(f0-mx0), ps1 = expg(f1-mx1), ps2 = expg(f2-mx2), ps3 = expg(f3-mx3);
  float i0 = 1.0f/(d0+ps0+1e-16f), i1 = 1.0f/(d1+ps1+1e-16f);
  float i2 = 1.0f/(d2+ps2+1e-16f), i3 = 1.0f/(d3+ps3+1e-16f);
  __syncthreads();   // sW visible to all lanes

  // accumulate: channels c=lane (heads 0/1) and c=64+lane (heads 2/3)
  int h0 = lane >> 5;
  float pA = h0 ? ps1 : ps0;
  float pB = h0 ? ps3 : ps2;
  float iA = h0 ? i1 : i0;
  float iB = h0 ? i3 : i2;
  float mA = h0 ? mx1 : mx0;
  float mB = h0 ? mx3 : mx2;
  float acc0 = 0.f, acc1 = 0.f;
  for (int e = 0; e < deg; ++e){
    float p0, p1;
    if (e < CAP){ p0 = sW[wid][e][h0]; p1 = sW[wid][e][2+h0]; }
    else {
      int ce = r + e;
      int src2 = csr_src[ce]; int eid2 = csr_eid[ce];
      float ae[4]; edge_ae4(eattr, eid2, sM, sC, ae);
      float4 as4 = *(const float4*)(a_src + (size_t)src2*4);
      float aa0 = h0 ? lrelu(as4.y + ad.y + ae[1]) : lrelu(as4.x + ad.x + ae[0]);
      float aa1 = h0 ? lrelu(as4.w + ad.w + ae[3]) : lrelu(as4.z + ad.z + ae[2]);
      p0 = expg(aa0 - mA); p1 = expg(aa1 - mB);
    }
    int src = csr_src[r + e];
    const float* xr = xh + (size_t)src*128;
    acc0 += p0 * xr[lane];
    acc1 += p1 * xr[64 + lane];
  }
  if (n < N){
    const float* xn = xh + (size_t)nn*128;
    acc0 += pA * xn[lane];
    acc1 += pB * xn[64 + lane];
    acc0 = acc0*iA + bconv[layer*128 + lane];
    acc1 = acc1*iB + bconv[layer*128 + 64 + lane];
    hout[(size_t)nn*128 + lane] = acc0;
    hout[(size_t)nn*128 + 64 + lane] = acc1;
  }
}

// ---------------- batch norm ----------------
__global__ __launch_bounds__(256) void bn_stats(const float* __restrict__ h, float* __restrict__ sum,
                                                float* __restrict__ sq, int N){
  int c = threadIdx.x & 127;
  int sub = threadIdx.x >> 7;
  float s = 0.f, q = 0.f;
  for (int n = blockIdx.x*2 + sub; n < N; n += gridDim.x*2){
    float v = h[(size_t)n*128 + c];
    s += v; q += v*v;
  }
  __shared__ float ls[256], lq[256];
  ls[threadIdx.x] = s; lq[threadIdx.x] = q;
  __syncthreads();
  if (threadIdx.x < 128){
    s = ls[threadIdx.x] + ls[threadIdx.x + 128];
    q = lq[threadIdx.x] + lq[threadIdx.x + 128];
    atomicAdd(&sum[c], s);
    atomicAdd(&sq[c], q);
  }
}
__global__ void bn_final(const float* __restrict__ sum, const float* __restrict__ sq,
                         const float* __restrict__ gamma, const float* __restrict__ beta,
                         float* __restrict__ scale, float* __restrict__ shift, int N){
  int c = threadIdx.x;
  float mean = sum[c] / (float)N;
  float var  = sq[c] / (float)N - mean*mean;
  var = fmaxf(var, 0.f);
  float rstd = rsqrtf(var + 1e-5f);
  float sc = gamma[c] * rstd;
  scale[c] = sc;
  shift[c] = beta[c] - mean*sc;
}
__global__ __launch_bounds__(256) void bn_elem(float* __restrict__ hg, const float* __restrict__ hprev,
                                               const float* __restrict__ scale, const float* __restrict__ shift,
                                               int total4){
  int i = blockIdx.x*256 + threadIdx.x;
  if (i >= total4) return;
  int c = (i*4) & 127;
  float4 v  = ((const float4*)hg)[i];
  float4 pv = ((const float4*)hprev)[i];
  float4 sc = *(const float4*)(scale + c);
  float4 sh = *(const float4*)(shift + c);
  float r0 = v.x*sc.x + sh.x; r0 = r0 > 0.f ? r0 : 0.f; r0 += pv.x;
  float r1 = v.y*sc.y + sh.y; r1 = r1 > 0.f ? r1 : 0.f; r1 += pv.y;
  float r2 = v.z*sc.z + sh.z; r2 = r2 > 0.f ? r2 : 0.f; r2 += pv.z;
  float r3 = v.w*sc.w + sh.w; r3 = r3 > 0.f ? r3 : 0.f; r3 += pv.w;
  float4 o; o.x = r0; o.y = r1; o.z = r2; o.w = r3;
  ((float4*)hg)[i] = o;
}

// ---------------- host ----------------
extern "C" void kernel_launch(void* const* d_in, const int* in_sizes, int n_in,
                              void* d_out, int out_size, void* d_ws, size_t ws_size,
                              hipStream_t stream)
{
  const void* x        = d_in[0];
  const int*  ei       = (const int*)d_in[1];
  const void* eattr    = d_in[2];
  int N = in_sizes[0] / 64;
  int E = in_sizes[1] / 2;

  char* p = (char*)d_ws;
  auto alloc = [&](size_t bytes)->char* {
    char* r = p; p += (bytes + 255) & ~(size_t)255; return r;
  };
  // zero-region first (one memset)
  int*   deg    = (int*)alloc((size_t)N*4);
  int*   cursor = (int*)alloc((size_t)N*4);
  float* bnsum  = (float*)alloc(3*128*4);
  float* bnsq   = (float*)alloc(3*128*4);
  size_t zbytes = (size_t)(p - (char*)deg);
  int*   dflag  = (int*)alloc(256);
  int*   row    = (int*)alloc(((size_t)N + 1)*4);
  int*   part   = (int*)alloc(1024*4);
  int*   csr_src= (int*)alloc((size_t)E*4);
  int*   csr_eid= (int*)alloc((size_t)E*4);
  float* hA     = (float*)alloc((size_t)N*128*4);
  float* hB     = (float*)alloc((size_t)N*128*4);
  float* xh     = (float*)alloc((size_t)N*128*4);
  float* a_src  = (float*)alloc((size_t)N*4*4);
  float* a_dst  = (float*)alloc((size_t)N*4*4);
  float* Mmat   = (float*)alloc(16*12*4);
  float* cbias  = (float*)alloc(12*4);
  float* bnscale= (float*)alloc(128*4);
  float* bnshift= (float*)alloc(128*4);
  unsigned short* xc  = (unsigned short*)alloc((size_t)N*64*2);
  unsigned short* eac = (unsigned short*)alloc((size_t)E*16*2);
  float* wc     = (float*)alloc(130000*4);

  // canonical weight buffers (fp32)
  int   woff[14] = {0, 8192, 8320, 10368, 10496, 59648, 108800, 109184,
                    109568, 109952, 110336, 110720, 111104, 127488};
  int   wcnt[14] = {8192, 128, 2048, 128, 49152, 49152, 384, 384, 384, 384, 384, 384, 16384, 128};
  // order: W_atom,b_atom,W_bond,b_bond,W_lin,W_edge,att_src,att_dst,att_edge,
  //        bias_conv,bn_gamma,bn_beta,W_out,b_out  = d_in[3..16]
  CvList L; L.n = 14;
  for (int a = 0; a < 14; ++a){ L.src[a] = d_in[3+a]; L.dst[a] = wc + woff[a]; L.cnt[a] = wcnt[a]; }
  float* cW_atom = wc + woff[0];  float* cb_atom = wc + woff[1];
  float* cW_bond = wc + woff[2];  float* cb_bond = wc + woff[3];
  float* cW_lin  = wc + woff[4];  float* cW_edge = wc + woff[5];
  float* catt_s  = wc + woff[6];  float* catt_d  = wc + woff[7];
  float* catt_e  = wc + woff[8];  float* cbconv  = wc + woff[9];
  float* cgamma  = wc + woff[10]; float* cbeta   = wc + woff[11];
  float* cW_out  = wc + woff[12]; float* cb_out  = wc + woff[13];

  hipMemsetAsync(deg, 0, zbytes, stream);
  detect_dtype<<<1, 64, 0, stream>>>((const unsigned short*)x, dflag);
  conv_weights<<<64, 256, 0, stream>>>(L, dflag);
  conv_bf16<<<(N*16 + 255)/256, 256, 0, stream>>>(x, xc, N*16, dflag);      // N*64/4
  conv_bf16<<<(E*4 + 255)/256, 256, 0, stream>>>(eattr, eac, E*4, dflag);   // E*16/4

  precompute_M<<<1, 256, 0, stream>>>(cW_edge, catt_e, cW_bond, cb_bond, Mmat, cbias);
  deg_count<<<(E + 255)/256, 256, 0, stream>>>(ei, E, deg);
  int P = (N + 1023)/1024;
  scan_part<<<P, 256, 0, stream>>>(deg, part, N);
  scan_top<<<1, 64, 0, stream>>>(part, P);
  scan_write<<<P, 256, 0, stream>>>(deg, part, row, N, E);
  csr_fill<<<(E + 255)/256, 256, 0, stream>>>(ei, E, row, cursor, csr_src, csr_eid);

  // atom embedding: hA = x @ W_atom + b_atom
  mfma_lin<64, false, 0><<<(N + 63)/64, 256, 0, stream>>>(xc, cW_atom, cb_atom, hA, N, dflag);

  float* cur = hA; float* oth = hB;
  for (int l = 0; l < 3; ++l){
    mfma_lin<128, true, 0><<<(N + 63)/64, 256, 0, stream>>>(cur, cW_lin + (size_t)l*16384, nullptr, xh, N, dflag);
    att_scores<<<4096, 128, 0, stream>>>(xh, catt_s + l*128, catt_d + l*128, a_src, a_dst, N);
    gat_agg<<<(N + 3)/4, 256, 0, stream>>>(xh, a_src, a_dst, row, csr_src, csr_eid, eac,
                                           Mmat, cbias, cbconv, oth, N, l);
    bn_stats<<<256, 256, 0, stream>>>(oth, bnsum + l*128, bnsq + l*128, N);
    bn_final<<<1, 128, 0, stream>>>(bnsum + l*128, bnsq + l*128, cgamma + l*128, cbeta + l*128,
                                    bnscale, bnshift, N);
    bn_elem<<<((N*128/4) + 255)/256, 256, 0, stream>>>(oth, cur, bnscale, bnshift, N*128/4);
    float* t = cur; cur = oth; oth = t;
  }
  // final projection, output dtype per detected storage
  mfma_lin<128, true, 1><<<(N + 63)/64, 256, 0, stream>>>(cur, cW_out, cb_out, d_out, N, dflag);
}

// Round 3
// 697.130 us; speedup vs baseline: 1.6196x; 1.6196x over previous
//
#include <hip/hip_runtime.h>
#include <stdint.h>

#define HID 128

typedef __attribute__((ext_vector_type(8))) short bf16x8;
typedef __attribute__((ext_vector_type(4))) float f32x4;

__device__ __forceinline__ float bf2f(unsigned short u){
  union { unsigned int i; float f; } x; x.i = ((unsigned int)u) << 16; return x.f;
}
__device__ __forceinline__ unsigned short f2bf(float f){
  union { float f; unsigned int i; } x; x.f = f;
  unsigned int b = x.i;
  return (unsigned short)((b + 0x7fffu + ((b >> 16) & 1u)) >> 16);
}

// ---------------- dtype detection: fp32 storage (flag=1) vs bf16 (flag=0) ----------------
__global__ void detect_dtype(const unsigned short* __restrict__ x, int* __restrict__ flag){
  if (threadIdx.x == 0 && blockIdx.x == 0){
    int czero = 0, cbig = 0;
    for (int i = 0; i < 256; ++i){
      unsigned short u = x[i];
      int ex = (u >> 7) & 0xFF;
      if ((i & 1) == 0 && u == 0) czero++;
      if (ex >= 140) cbig++;
    }
    flag[0] = (czero >= 32 || cbig >= 8) ? 1 : 0;
  }
}

// ---------------- canonicalization ----------------
struct CvList {
  const void* src[16];
  float* dst[16];
  int cnt[16];
  int n;
};
__global__ __launch_bounds__(256) void conv_weights(CvList L, const int* __restrict__ flag){
  bool isf32 = flag[0] != 0;
  for (int a = 0; a < L.n; ++a){
    const void* s = L.src[a];
    float* d = L.dst[a];
    int c = L.cnt[a];
    for (int i = blockIdx.x*256 + threadIdx.x; i < c; i += gridDim.x*256){
      d[i] = isf32 ? ((const float*)s)[i] : bf2f(((const unsigned short*)s)[i]);
    }
  }
}
__global__ __launch_bounds__(256) void conv_bf16(const void* __restrict__ src,
                                                 unsigned short* __restrict__ dst,
                                                 int n4, const int* __restrict__ flag){
  int i = blockIdx.x*256 + threadIdx.x;
  if (i >= n4) return;
  if (flag[0]){
    float4 v = ((const float4*)src)[i];
    ushort4 o; o.x = f2bf(v.x); o.y = f2bf(v.y); o.z = f2bf(v.z); o.w = f2bf(v.w);
    ((ushort4*)dst)[i] = o;
  } else {
    ((ushort4*)dst)[i] = ((const ushort4*)src)[i];
  }
}

// ---------------- precompute M = W_bond @ (W_edge @ att_edge), cbias = b_bond @ ve ----
__global__ __launch_bounds__(256) void precompute_M(
    const float* __restrict__ We, const float* __restrict__ ae,
    const float* __restrict__ Wb, const float* __restrict__ bb,
    float* __restrict__ Mout, float* __restrict__ cb)
{
  __shared__ float ve[128*12];
  int tid = threadIdx.x;
  for (int i = tid; i < 128*12; i += 256){
    int c = i / 12, lh = i % 12; int l = lh >> 2, h = lh & 3;
    float s = 0.f;
    for (int d = 0; d < 32; ++d)
      s += We[l*16384 + c*128 + h*32 + d] * ae[l*128 + h*32 + d];
    ve[i] = s;
  }
  __syncthreads();
  for (int i = tid; i < 16*12; i += 256){
    int k = i / 12, lh = i % 12;
    float s = 0.f;
    for (int c = 0; c < 128; ++c) s += Wb[k*128 + c] * ve[c*12 + lh];
    Mout[i] = s;
  }
  for (int i = tid; i < 12; i += 256){
    float s = 0.f;
    for (int c = 0; c < 128; ++c) s += bb[c] * ve[c*12 + i];
    cb[i] = s;
  }
}

// ---------------- CSR build ----------------
__global__ __launch_bounds__(256) void deg_count(const int* __restrict__ ei, int E, int* __restrict__ deg){
  int e = blockIdx.x*256 + threadIdx.x;
  if (e < E) atomicAdd(&deg[ei[E + e]], 1);
}
__global__ __launch_bounds__(256) void scan_part(const int* __restrict__ deg, int* __restrict__ part, int N){
  int base = blockIdx.x*1024;
  int s = 0;
  for (int i = threadIdx.x; i < 1024; i += 256){ int j = base + i; if (j < N) s += deg[j]; }
  __shared__ int sh[256];
  sh[threadIdx.x] = s; __syncthreads();
  for (int m = 128; m > 0; m >>= 1){ if (threadIdx.x < m) sh[threadIdx.x] += sh[threadIdx.x + m]; __syncthreads(); }
  if (threadIdx.x == 0) part[blockIdx.x] = sh[0];
}
__global__ void scan_top(int* part, int P){
  if (threadIdx.x == 0 && blockIdx.x == 0){
    int acc = 0;
    for (int i = 0; i < P; ++i){ int v = part[i]; part[i] = acc; acc += v; }
  }
}
__global__ __launch_bounds__(256) void scan_write(const int* __restrict__ deg, const int* __restrict__ part,
                                                  int* __restrict__ row, int N, int E){
  int base = blockIdx.x*1024 + threadIdx.x*4;
  int v0=0,v1=0,v2=0,v3=0;
  if (base+0 < N) v0 = deg[base+0];
  if (base+1 < N) v1 = deg[base+1];
  if (base+2 < N) v2 = deg[base+2];
  if (base+3 < N) v3 = deg[base+3];
  int s = v0+v1+v2+v3;
  __shared__ int sh[256];
  sh[threadIdx.x] = s; __syncthreads();
  for (int m = 1; m < 256; m <<= 1){
    int t = (threadIdx.x >= m) ? sh[threadIdx.x - m] : 0;
    __syncthreads();
    sh[threadIdx.x] += t;
    __syncthreads();
  }
  int excl = sh[threadIdx.x] - s + part[blockIdx.x];
  if (base+0 < N) row[base+0] = excl; excl += v0;
  if (base+1 < N) row[base+1] = excl; excl += v1;
  if (base+2 < N) row[base+2] = excl; excl += v2;
  if (base+3 < N) row[base+3] = excl;
  if (blockIdx.x == 0 && threadIdx.x == 0) row[N] = E;
}
__global__ __launch_bounds__(256) void csr_fill(const int* __restrict__ ei, int E, const int* __restrict__ row,
                                                int* __restrict__ cursor, int* __restrict__ csr_src,
                                                int* __restrict__ csr_eid, int* __restrict__ csr_dst){
  int e = blockIdx.x*256 + threadIdx.x;
  if (e >= E) return;
  int s = ei[e], d = ei[E + e];
  int pos = atomicAdd(&cursor[d], 1);
  int idx = row[d] + pos;
  csr_src[idx] = s;
  csr_eid[idx] = e;
  csr_dst[idx] = d;
}

// ---------------- MFMA GEMM: out[N,128] = A[N,K] @ W[K,128] (+bias) ----------------
// OUTMODE: 0 = fp32 internal buffer, 1 = external output, dtype per flag (1=fp32,0=bf16)
template<int K, bool INF32, int OUTMODE>
__global__ __launch_bounds__(256) void mfma_lin(const void* __restrict__ Ain,
                                                const float* __restrict__ W,
                                                const float* __restrict__ bias,
                                                void* __restrict__ Out, int N,
                                                const int* __restrict__ flag)
{
  constexpr int KP = K + 8;
  __shared__ unsigned short WT[128*KP];
  int tid = threadIdx.x;
  for (int i = tid; i < K*128; i += 256){
    int k = i >> 7, ch = i & 127;
    WT[ch*KP + k] = f2bf(W[i]);
  }
  __syncthreads();
  int wid = tid >> 6, lane = tid & 63;
  int quad = lane >> 4, m = lane & 15;
  int nodeBase = blockIdx.x*64 + wid*16;
  int node = nodeBase + m;
  int nodeC = (node < N) ? node : 0;
  bf16x8 afr[K/32];
  if (INF32){
    const float* A = (const float*)Ain;
    #pragma unroll
    for (int kb = 0; kb < K/32; ++kb){
      const float4* pp = (const float4*)(A + (size_t)nodeC*K + kb*32 + quad*8);
      float4 u = pp[0], v = pp[1];
      bf16x8 f;
      f[0]=(short)f2bf(u.x); f[1]=(short)f2bf(u.y); f[2]=(short)f2bf(u.z); f[3]=(short)f2bf(u.w);
      f[4]=(short)f2bf(v.x); f[5]=(short)f2bf(v.y); f[6]=(short)f2bf(v.z); f[7]=(short)f2bf(v.w);
      afr[kb] = f;
    }
  } else {
    const unsigned short* A = (const unsigned short*)Ain;
    #pragma unroll
    for (int kb = 0; kb < K/32; ++kb)
      afr[kb] = *(const bf16x8*)(A + (size_t)nodeC*K + kb*32 + quad*8);
  }
  f32x4 acc[8] = {};
  #pragma unroll
  for (int t = 0; t < 8; ++t){
    #pragma unroll
    for (int kb = 0; kb < K/32; ++kb){
      bf16x8 bfr = *(const bf16x8*)&WT[(t*16 + m)*KP + kb*32 + quad*8];
      acc[t] = __builtin_amdgcn_mfma_f32_16x16x32_bf16(afr[kb], bfr, acc[t], 0, 0, 0);
    }
  }
  bool f32out = (OUTMODE == 0) || (flag[0] != 0);
  #pragma unroll
  for (int t = 0; t < 8; ++t){
    int ch = t*16 + m;
    float bv = bias ? bias[ch] : 0.f;
    #pragma unroll
    for (int r2 = 0; r2 < 4; ++r2){
      int nd = nodeBase + quad*4 + r2;
      if (nd < N){
        float v = acc[t][r2] + bv;
        if (f32out) ((float*)Out)[(size_t)nd*HID + ch] = v;
        else        ((unsigned short*)Out)[(size_t)nd*HID + ch] = f2bf(v);
      }
    }
  }
}

// ---------------- per-head attention scores a_src/a_dst [N,4] ----------------
__global__ __launch_bounds__(128) void att_scores(const float* __restrict__ xh,
                                                  const float* __restrict__ asv,
                                                  const float* __restrict__ adv,
                                                  float* __restrict__ a_src, float* __restrict__ a_dst, int N)
{
  int c = threadIdx.x;
  float sa = asv[c], da = adv[c];
  for (int n = blockIdx.x; n < N; n += gridDim.x){
    float v = xh[(size_t)n*128 + c];
    float vs = v * sa, vd = v * da;
    #pragma unroll
    for (int m = 1; m < 32; m <<= 1){ vs += __shfl_xor(vs, m); vd += __shfl_xor(vd, m); }
    if ((c & 31) == 0){
      a_src[(size_t)n*4 + (c >> 5)] = vs;
      a_dst[(size_t)n*4 + (c >> 5)] = vd;
    }
  }
}

__device__ __forceinline__ float lrelu(float x){ return x > 0.f ? x : 0.2f*x; }
__device__ __forceinline__ float expg(float x){ return __expf(fminf(x, 0.f)); }

// ---------------- edge-parallel alpha: alpha[pos], ae[pos] in CSR order ----------------
__global__ __launch_bounds__(256) void edge_alpha(
    const void* __restrict__ eattr,
    const int* __restrict__ csr_src, const int* __restrict__ csr_eid, const int* __restrict__ csr_dst,
    const float* __restrict__ a_src, const float* __restrict__ a_dst,
    const float* __restrict__ Mmat, const float* __restrict__ cbias,
    float4* __restrict__ alphaA, float4* __restrict__ aeA,
    int E, int layer, const int* __restrict__ flag)
{
  __shared__ float sM[16][4];
  __shared__ float sC[4];
  int tid = threadIdx.x;
  if (tid < 64) sM[tid>>2][tid&3] = Mmat[(tid>>2)*12 + layer*4 + (tid&3)];
  if (tid < 4)  sC[tid] = cbias[layer*4 + tid];
  __syncthreads();
  int pos = blockIdx.x*256 + tid;
  if (pos >= E) return;
  int src = csr_src[pos], eid = csr_eid[pos], dst = csr_dst[pos];
  float v[16];
  if (flag[0]){
    const float4* pp = (const float4*)((const float*)eattr + (size_t)eid*16);
    float4 u0 = pp[0], u1 = pp[1], u2 = pp[2], u3 = pp[3];
    v[0]=u0.x; v[1]=u0.y; v[2]=u0.z; v[3]=u0.w;
    v[4]=u1.x; v[5]=u1.y; v[6]=u1.z; v[7]=u1.w;
    v[8]=u2.x; v[9]=u2.y; v[10]=u2.z; v[11]=u2.w;
    v[12]=u3.x; v[13]=u3.y; v[14]=u3.z; v[15]=u3.w;
  } else {
    const uint4* pp = (const uint4*)((const unsigned short*)eattr + (size_t)eid*16);
    uint4 u0 = pp[0], u1 = pp[1];
    unsigned int w[8] = {u0.x,u0.y,u0.z,u0.w,u1.x,u1.y,u1.z,u1.w};
    #pragma unroll
    for (int k = 0; k < 16; ++k)
      v[k] = bf2f((unsigned short)((k & 1) ? (w[k>>1] >> 16) : (w[k>>1] & 0xffffu)));
  }
  float ae0 = sC[0], ae1 = sC[1], ae2 = sC[2], ae3 = sC[3];
  #pragma unroll
  for (int k = 0; k < 16; ++k){
    ae0 += v[k]*sM[k][0]; ae1 += v[k]*sM[k][1];
    ae2 += v[k]*sM[k][2]; ae3 += v[k]*sM[k][3];
  }
  float4 as4 = *(const float4*)(a_src + (size_t)src*4);
  float4 ad4 = *(const float4*)(a_dst + (size_t)dst*4);
  float4 al;
  al.x = lrelu(as4.x + ad4.x + ae0);
  al.y = lrelu(as4.y + ad4.y + ae1);
  al.z = lrelu(as4.z + ad4.z + ae2);
  al.w = lrelu(as4.w + ad4.w + ae3);
  alphaA[pos] = al;
  float4 aev; aev.x = ae0; aev.y = ae1; aev.z = ae2; aev.w = ae3;
  aeA[pos] = aev;
}

// ---------------- GAT aggregation v2: wave per node, softmax from contiguous alpha ----
__global__ __launch_bounds__(256) void gat_agg(
    const float* __restrict__ xh,
    const float4* __restrict__ alphaA, const float4* __restrict__ aeA,
    const int* __restrict__ csr_src, const int* __restrict__ row,
    const float* __restrict__ a_src, const float* __restrict__ a_dst,
    const float* __restrict__ bconv, float* __restrict__ hout, int N, int layer)
{
  __shared__ float sPf[4][256];   // p per edge (4 heads)
  __shared__ int   sS[4][64];     // src per edge
  int tid = threadIdx.x;
  int wid = tid >> 6, lane = tid & 63;
  int n = blockIdx.x*4 + wid;
  int nn = (n < N) ? n : 0;
  int r = row[nn];
  int deg = row[nn+1] - r;
  if (n >= N) deg = 0;

  // load this lane's edge (first 64)
  float4 aL; aL.x = aL.y = aL.z = aL.w = -1e30f;
  float4 aeL; aeL.x = aeL.y = aeL.z = aeL.w = 0.f;
  int mysrc = 0;
  if (lane < deg){
    aL  = alphaA[r + lane];
    aeL = aeA[r + lane];
    mysrc = csr_src[r + lane];
  }
  float mx0 = aL.x, mx1 = aL.y, mx2 = aL.z, mx3 = aL.w;
  float s0 = aeL.x, s1 = aeL.y, s2 = aeL.z, s3 = aeL.w;
  for (int e = lane + 64; e < deg; e += 64){   // essentially never taken (deg~12)
    float4 t = alphaA[r + e];
    float4 u = aeA[r + e];
    mx0 = fmaxf(mx0, t.x); mx1 = fmaxf(mx1, t.y); mx2 = fmaxf(mx2, t.z); mx3 = fmaxf(mx3, t.w);
    s0 += u.x; s1 += u.y; s2 += u.z; s3 += u.w;
  }
  #pragma unroll
  for (int m = 1; m < 64; m <<= 1){
    mx0 = fmaxf(mx0, __shfl_xor(mx0,m)); mx1 = fmaxf(mx1, __shfl_xor(mx1,m));
    mx2 = fmaxf(mx2, __shfl_xor(mx2,m)); mx3 = fmaxf(mx3, __shfl_xor(mx3,m));
    s0 += __shfl_xor(s0,m); s1 += __shfl_xor(s1,m); s2 += __shfl_xor(s2,m); s3 += __shfl_xor(s3,m);
  }
  // self-loop: ae = mean of incoming ae (0 if deg==0, matching ref's /max(deg,1) on zeros)
  float invdeg = (deg > 0) ? 1.0f/(float)deg : 0.0f;
  float4 asn = *(const float4*)(a_src + (size_t)nn*4);
  float4 adn = *(const float4*)(a_dst + (size_t)nn*4);
  float f0 = lrelu(asn.x + adn.x + s0*invdeg);
  float f1 = lrelu(asn.y + adn.y + s1*invdeg);
  float f2 = lrelu(asn.z + adn.z + s2*invdeg);
  float f3 = lrelu(asn.w + adn.w + s3*invdeg);
  mx0 = fmaxf(mx0,f0); mx1 = fmaxf(mx1,f1); mx2 = fmaxf(mx2,f2); mx3 = fmaxf(mx3,f3);

  // p for this lane's edge; write LDS cache
  float p0 = 0.f, p1 = 0.f, p2 = 0.f, p3 = 0.f;
  if (lane < deg){
    p0 = expg(aL.x - mx0); p1 = expg(aL.y - mx1);
    p2 = expg(aL.z - mx2); p3 = expg(aL.w - mx3);
    sPf[wid][lane*4 + 0] = p0; sPf[wid][lane*4 + 1] = p1;
    sPf[wid][lane*4 + 2] = p2; sPf[wid][lane*4 + 3] = p3;
    sS[wid][lane] = mysrc;
  }
  float d0 = p0, d1 = p1, d2 = p2, d3 = p3;
  for (int e = lane + 64; e < deg; e += 64){
    float4 t = alphaA[r + e];
    d0 += expg(t.x - mx0); d1 += expg(t.y - mx1);
    d2 += expg(t.z - mx2); d3 += expg(t.w - mx3);
  }
  #pragma unroll
  for (int m = 1; m < 64; m <<= 1){
    d0 += __shfl_xor(d0,m); d1 += __shfl_xor(d1,m); d2 += __shfl_xor(d2,m); d3 += __shfl_xor(d3,m);
  }
  float ps0 = expg(f0-mx0), ps1 = expg(f1-mx1), ps2 = expg(f2-mx2), ps3 = expg(f3-mx3);
  float i0 = 1.0f/(d0+ps0+1e-16f), i1 = 1.0f/(d1+ps1+1e-16f);
  float i2 = 1.0f/(d2+ps2+1e-16f), i3 = 1.0f/(d3+ps3+1e-16f);

  // aggregation: lane handles channels c=2*lane, 2*lane+1; head h = lane>>4
  int h = lane >> 4;
  float psh = h==0 ? ps0 : h==1 ? ps1 : h==2 ? ps2 : ps3;
  float ih  = h==0 ? i0  : h==1 ? i1  : h==2 ? i2  : i3;
  float mxh = h==0 ? mx0 : h==1 ? mx1 : h==2 ? mx2 : mx3;
  float acc0 = 0.f, acc1 = 0.f;
  int dmin = deg < 64 ? deg : 64;
  int e = 0;
  for (; e + 4 <= dmin; e += 4){
    int sA = sS[wid][e+0], sB = sS[wid][e+1], sC2 = sS[wid][e+2], sD = sS[wid][e+3];
    float qA = sPf[wid][(e+0)*4 + h];
    float qB = sPf[wid][(e+1)*4 + h];
    float qC = sPf[wid][(e+2)*4 + h];
    float qD = sPf[wid][(e+3)*4 + h];
    float2 xA = *(const float2*)(xh + (size_t)sA*128 + 2*lane);
    float2 xB = *(const float2*)(xh + (size_t)sB*128 + 2*lane);
    float2 xC = *(const float2*)(xh + (size_t)sC2*128 + 2*lane);
    float2 xD = *(const float2*)(xh + (size_t)sD*128 + 2*lane);
    acc0 += qA*xA.x + qB*xB.x + qC*xC.x + qD*xD.x;
    acc1 += qA*xA.y + qB*xB.y + qC*xC.y + qD*xD.y;
  }
  for (; e < dmin; ++e){
    int s = sS[wid][e];
    float q = sPf[wid][e*4 + h];
    float2 xv = *(const float2*)(xh + (size_t)s*128 + 2*lane);
    acc0 += q*xv.x; acc1 += q*xv.y;
  }
  for (; e < deg; ++e){   // deg>64 fallback
    float4 t = alphaA[r + e];
    float av = h==0 ? t.x : h==1 ? t.y : h==2 ? t.z : t.w;
    float q = expg(av - mxh);
    int s = csr_src[r + e];
    float2 xv = *(const float2*)(xh + (size_t)s*128 + 2*lane);
    acc0 += q*xv.x; acc1 += q*xv.y;
  }
  if (n < N){
    float2 xn = *(const float2*)(xh + (size_t)nn*128 + 2*lane);
    acc0 += psh * xn.x;
    acc1 += psh * xn.y;
    float2 bc = *(const float2*)(bconv + layer*128 + 2*lane);
    acc0 = acc0*ih + bc.x;
    acc1 = acc1*ih + bc.y;
    float2 o; o.x = acc0; o.y = acc1;
    *(float2*)(hout + (size_t)nn*128 + 2*lane) = o;
  }
}

// ---------------- batch norm ----------------
__global__ __launch_bounds__(256) void bn_stats(const float* __restrict__ h, float* __restrict__ sum,
                                                float* __restrict__ sq, int N){
  int c = threadIdx.x & 127;
  int sub = threadIdx.x >> 7;
  float s = 0.f, q = 0.f;
  for (int n = blockIdx.x*2 + sub; n < N; n += gridDim.x*2){
    float v = h[(size_t)n*128 + c];
    s += v; q += v*v;
  }
  __shared__ float ls[256], lq[256];
  ls[threadIdx.x] = s; lq[threadIdx.x] = q;
  __syncthreads();
  if (threadIdx.x < 128){
    s = ls[threadIdx.x] + ls[threadIdx.x + 128];
    q = lq[threadIdx.x] + lq[threadIdx.x + 128];
    atomicAdd(&sum[c], s);
    atomicAdd(&sq[c], q);
  }
}
__global__ void bn_final(const float* __restrict__ sum, const float* __restrict__ sq,
                         const float* __restrict__ gamma, const float* __restrict__ beta,
                         float* __restrict__ scale, float* __restrict__ shift, int N){
  int c = threadIdx.x;
  float mean = sum[c] / (float)N;
  float var  = sq[c] / (float)N - mean*mean;
  var = fmaxf(var, 0.f);
  float rstd = rsqrtf(var + 1e-5f);
  float sc = gamma[c] * rstd;
  scale[c] = sc;
  shift[c] = beta[c] - mean*sc;
}
__global__ __launch_bounds__(256) void bn_elem(float* __restrict__ hg, const float* __restrict__ hprev,
                                               const float* __restrict__ scale, const float* __restrict__ shift,
                                               int total4){
  int i = blockIdx.x*256 + threadIdx.x;
  if (i >= total4) return;
  int c = (i*4) & 127;
  float4 v  = ((const float4*)hg)[i];
  float4 pv = ((const float4*)hprev)[i];
  float4 sc = *(const float4*)(scale + c);
  float4 sh = *(const float4*)(shift + c);
  float r0 = v.x*sc.x + sh.x; r0 = r0 > 0.f ? r0 : 0.f; r0 += pv.x;
  float r1 = v.y*sc.y + sh.y; r1 = r1 > 0.f ? r1 : 0.f; r1 += pv.y;
  float r2 = v.z*sc.z + sh.z; r2 = r2 > 0.f ? r2 : 0.f; r2 += pv.z;
  float r3 = v.w*sc.w + sh.w; r3 = r3 > 0.f ? r3 : 0.f; r3 += pv.w;
  float4 o; o.x = r0; o.y = r1; o.z = r2; o.w = r3;
  ((float4*)hg)[i] = o;
}

// ---------------- host ----------------
extern "C" void kernel_launch(void* const* d_in, const int* in_sizes, int n_in,
                              void* d_out, int out_size, void* d_ws, size_t ws_size,
                              hipStream_t stream)
{
  const void* x        = d_in[0];
  const int*  ei       = (const int*)d_in[1];
  const void* eattr    = d_in[2];
  int N = in_sizes[0] / 64;
  int E = in_sizes[1] / 2;

  char* p = (char*)d_ws;
  auto alloc = [&](size_t bytes)->char* {
    char* r = p; p += (bytes + 255) & ~(size_t)255; return r;
  };
  // zero-region first (one memset)
  int*   deg    = (int*)alloc((size_t)N*4);
  int*   cursor = (int*)alloc((size_t)N*4);
  float* bnsum  = (float*)alloc(3*128*4);
  float* bnsq   = (float*)alloc(3*128*4);
  size_t zbytes = (size_t)(p - (char*)deg);
  int*   dflag  = (int*)alloc(256);
  int*   row    = (int*)alloc(((size_t)N + 1)*4);
  int*   part   = (int*)alloc(1024*4);
  int*   csr_src= (int*)alloc((size_t)E*4);
  int*   csr_eid= (int*)alloc((size_t)E*4);
  int*   csr_dst= (int*)alloc((size_t)E*4);
  float* hA     = (float*)alloc((size_t)N*128*4);
  float* hB     = (float*)alloc((size_t)N*128*4);
  float* xh     = (float*)alloc((size_t)N*128*4);
  float* a_src  = (float*)alloc((size_t)N*4*4);
  float* a_dst  = (float*)alloc((size_t)N*4*4);
  float4* alphaA= (float4*)alloc((size_t)E*16);
  float4* aeA   = (float4*)alloc((size_t)E*16);
  float* Mmat   = (float*)alloc(16*12*4);
  float* cbias  = (float*)alloc(12*4);
  float* bnscale= (float*)alloc(128*4);
  float* bnshift= (float*)alloc(128*4);
  unsigned short* xc  = (unsigned short*)alloc((size_t)N*64*2);
  float* wc     = (float*)alloc(130000*4);

  // canonical weight buffers (fp32)
  int   woff[14] = {0, 8192, 8320, 10368, 10496, 59648, 108800, 109184,
                    109568, 109952, 110336, 110720, 111104, 127488};
  int   wcnt[14] = {8192, 128, 2048, 128, 49152, 49152, 384, 384, 384, 384, 384, 384, 16384, 128};
  CvList L; L.n = 14;
  for (int a = 0; a < 14; ++a){ L.src[a] = d_in[3+a]; L.dst[a] = wc + woff[a]; L.cnt[a] = wcnt[a]; }
  float* cW_atom = wc + woff[0];  float* cb_atom = wc + woff[1];
  float* cW_bond = wc + woff[2];  float* cb_bond = wc + woff[3];
  float* cW_lin  = wc + woff[4];  float* cW_edge = wc + woff[5];
  float* catt_s  = wc + woff[6];  float* catt_d  = wc + woff[7];
  float* catt_e  = wc + woff[8];  float* cbconv  = wc + woff[9];
  float* cgamma  = wc + woff[10]; float* cbeta   = wc + woff[11];
  float* cW_out  = wc + woff[12]; float* cb_out  = wc + woff[13];

  hipMemsetAsync(deg, 0, zbytes, stream);
  detect_dtype<<<1, 64, 0, stream>>>((const unsigned short*)x, dflag);
  conv_weights<<<64, 256, 0, stream>>>(L, dflag);
  conv_bf16<<<(N*16 + 255)/256, 256, 0, stream>>>(x, xc, N*16, dflag);

  precompute_M<<<1, 256, 0, stream>>>(cW_edge, catt_e, cW_bond, cb_bond, Mmat, cbias);
  deg_count<<<(E + 255)/256, 256, 0, stream>>>(ei, E, deg);
  int P = (N + 1023)/1024;
  scan_part<<<P, 256, 0, stream>>>(deg, part, N);
  scan_top<<<1, 64, 0, stream>>>(part, P);
  scan_write<<<P, 256, 0, stream>>>(deg, part, row, N, E);
  csr_fill<<<(E + 255)/256, 256, 0, stream>>>(ei, E, row, cursor, csr_src, csr_eid, csr_dst);

  // atom embedding: hA = x @ W_atom + b_atom
  mfma_lin<64, false, 0><<<(N + 63)/64, 256, 0, stream>>>(xc, cW_atom, cb_atom, hA, N, dflag);

  float* cur = hA; float* oth = hB;
  for (int l = 0; l < 3; ++l){
    mfma_lin<128, true, 0><<<(N + 63)/64, 256, 0, stream>>>(cur, cW_lin + (size_t)l*16384, nullptr, xh, N, dflag);
    att_scores<<<4096, 128, 0, stream>>>(xh, catt_s + l*128, catt_d + l*128, a_src, a_dst, N);
    edge_alpha<<<(E + 255)/256, 256, 0, stream>>>(eattr, csr_src, csr_eid, csr_dst,
                                                  a_src, a_dst, Mmat, cbias, alphaA, aeA, E, l, dflag);
    gat_agg<<<(N + 3)/4, 256, 0, stream>>>(xh, alphaA, aeA, csr_src, row, a_src, a_dst,
                                           cbconv, oth, N, l);
    bn_stats<<<256, 256, 0, stream>>>(oth, bnsum + l*128, bnsq + l*128, N);
    bn_final<<<1, 128, 0, stream>>>(bnsum + l*128, bnsq + l*128, cgamma + l*128, cbeta + l*128,
                                    bnscale, bnshift, N);
    bn_elem<<<((N*128/4) + 255)/256, 256, 0, stream>>>(oth, cur, bnscale, bnshift, N*128/4);
    float* t = cur; cur = oth; oth = t;
  }
  // final projection, output dtype per detected storage
  mfma_lin<128, true, 1><<<(N + 63)/64, 256, 0, stream>>>(cur, cW_out, cb_out, d_out, N, dflag);
}